// Round 21
// baseline (139.212 us; speedup 1.0000x reference)
//
#include <hip/hip_runtime.h>
#include <math.h>

#define Bn 4
#define Sn 2048
#define Dn 1024
#define Hn 16
#define DHn 64
#define KT 64            // keys per tile
#define STR 72           // padded ushort stride for row-major scratch

typedef __attribute__((ext_vector_type(8))) short short8;
typedef __attribute__((ext_vector_type(4))) float f32x4;

__device__ __forceinline__ ushort f2bf(float f) {
    union { float f; unsigned u; } x; x.f = f;
    unsigned r = x.u + 0x7fffu + ((x.u >> 16) & 1u);   // RNE
    return (ushort)(r >> 16);
}

__device__ __forceinline__ unsigned pack_bf2(float lo, float hi) {
    unsigned r;
    asm("v_cvt_pk_bf16_f32 %0, %1, %2" : "=v"(r) : "v"(lo), "v"(hi));
    return r;
}

// r12: native v_exp_f32
__device__ __forceinline__ float fexp2(float x) { return __builtin_amdgcn_exp2f(x); }

// r13: 2-op masked score
__device__ __forceinline__ float mask_sel(unsigned nib, int r, float s) {
    int sx; unsigned tb;
    asm("v_bfe_i32 %0, %1, %2, 1" : "=v"(sx) : "v"(nib), "i"(r));
    asm("v_bfi_b32 %0, %1, 0, %2" : "=v"(tb) : "v"(sx), "v"(__float_as_uint(s)));
    return __uint_as_float(tb);
}

// ============ fused prep: blocks [0,2048) fragment-major K/V; [2048,6144) bitpack masks ============
__global__ __launch_bounds__(256)
void prep_fused(const float* __restrict__ xin, const float* __restrict__ pK,
                const float* __restrict__ pV, const int* __restrict__ masks,
                ushort* __restrict__ Kw, ushort* __restrict__ Vw,
                unsigned long long* __restrict__ mpack)
{
    __shared__ ushort LK[64 * STR];
    __shared__ ushort LV[64 * STR];
    const int t = threadIdx.x;

    if (blockIdx.x >= 2048) {
        const int l = t & 63;
        const int wid_g = ((blockIdx.x - 2048) * 256 + t) >> 6;
        #pragma unroll 4
        for (int i = 0; i < 16; ++i) {
            int word = wid_g * 16 + i;
            int row  = word >> 5, wd = word & 31;
            int m = masks[(size_t)row * 2048 + wd * 64 + l];
            unsigned long long bits = __ballot(m != 0);
            if (l == 0) mpack[word] = bits;
        }
        return;
    }

    const int kt = blockIdx.x & 31, n = blockIdx.x >> 5, b = n >> 4, h = n & 15;
    const int sl = t >> 2, dq = (t & 3) * 16;

    const float* xp  = xin + ((size_t)b * Sn + kt * 64 + sl) * Dn + h * DHn + dq;
    const float* pkp = pK + h * DHn + dq;
    const float* pvp = pV + h * DHn + dq;

    float xv[16], pk[16], pv[16];
    #pragma unroll
    for (int j = 0; j < 4; ++j) {
        float4 a  = ((const float4*)xp)[j];
        float4 kk = ((const float4*)pkp)[j];
        float4 vv = ((const float4*)pvp)[j];
        xv[4*j+0] = a.x;  xv[4*j+1] = a.y;  xv[4*j+2] = a.z;  xv[4*j+3] = a.w;
        pk[4*j+0] = kk.x; pk[4*j+1] = kk.y; pk[4*j+2] = kk.z; pk[4*j+3] = kk.w;
        pv[4*j+0] = vv.x; pv[4*j+1] = vv.y; pv[4*j+2] = vv.z; pv[4*j+3] = vv.w;
    }
    unsigned kw[8], vw[8];
    #pragma unroll
    for (int j = 0; j < 8; ++j) {
        kw[j] = pack_bf2(xv[2*j] * pk[2*j], xv[2*j+1] * pk[2*j+1]);
        vw[j] = pack_bf2(xv[2*j] * pv[2*j], xv[2*j+1] * pv[2*j+1]);
    }
    *(uint4*)&LK[sl * STR + dq]     = make_uint4(kw[0], kw[1], kw[2], kw[3]);
    *(uint4*)&LK[sl * STR + dq + 8] = make_uint4(kw[4], kw[5], kw[6], kw[7]);
    *(uint4*)&LV[sl * STR + dq]     = make_uint4(vw[0], vw[1], vw[2], vw[3]);
    *(uint4*)&LV[sl * STR + dq + 8] = make_uint4(vw[4], vw[5], vw[6], vw[7]);
    __syncthreads();

    ushort* kout = Kw + ((size_t)n * 32 + kt) * 4096;
    ushort* vout = Vw + ((size_t)n * 32 + kt) * 4096;
    #pragma unroll
    for (int i = 0; i < 2; ++i) {
        int c  = t * 2 + i;
        int f  = c >> 6, lc = c & 63;
        int key = (f >> 1) * 16 + (lc & 15);
        int dh0 = (f & 1) * 32 + (lc >> 4) * 8;
        *(uint4*)(kout + c * 8) = *(const uint4*)&LK[key * STR + dh0];
        int dg = f & 3, hh = f >> 2;
        int dhv = dg * 16 + (lc & 15);
        ushort tmp[8];
        #pragma unroll
        for (int e = 0; e < 8; ++e) {
            int p  = hh * 32 + (lc >> 4) * 8 + e;
            int ss = (p & 32) | ((p & 4) << 2) | ((p & 24) >> 1) | (p & 3);
            tmp[e] = LV[ss * STR + dhv];
        }
        unsigned o0 = (unsigned)tmp[0] | ((unsigned)tmp[1] << 16);
        unsigned o1 = (unsigned)tmp[2] | ((unsigned)tmp[3] << 16);
        unsigned o2 = (unsigned)tmp[4] | ((unsigned)tmp[5] << 16);
        unsigned o3 = (unsigned)tmp[6] | ((unsigned)tmp[7] << 16);
        *(uint4*)(vout + c * 8) = make_uint4(o0, o1, o2, o3);
    }
}

// ============ attn7: 8-wave in-block split-K, CORRECTED launch bounds ============
// r19 post-mortem: (512,4) capped VGPRs at 256/4 = 64 for a 128-reg working set
// (cap formula verified against 5 rounds: (256,4)->64, (256,2)->100/128,
// (256,3)->84, (512,4)->64). Fix: (512,2) -> cap 128, matching r18's footprint.
// HW can still co-schedule 2 blocks/CU (16 waves x 128 VGPR = pool; LDS 128KB).
// Algebra already HW-verified correct in r19's spilled run (passed, absmax .033).
__global__ __launch_bounds__(512, 2)
void attn_fast7(const float* __restrict__ xin, const unsigned long long* __restrict__ mpack,
                const float* __restrict__ pQ, const ushort* __restrict__ Kw,
                const ushort* __restrict__ Vw, float* __restrict__ out)
{
    // S (64KB = 32768 ushorts):
    //  - Q scratch phase: rows [0,256) x STR (36.9KB)
    //  - main loop: stream A [0,16384): K0|K1|V0|V1 (4096 each); stream B [16384,32768)
    //  - combine phase (as float*): 4 rounds x 5120 f32 (20KB)
    __shared__ __attribute__((aligned(16))) ushort S[32768];

    const int id   = blockIdx.x;
    const int xcd  = id & 7, pos = id >> 3;     // 512 blocks: pos 0..63
    const int n    = (pos >> 3) * 8 + xcd;      // head-locality per XCD
    const int q0   = (pos & 7) * 256;
    const int b    = n >> 4;
    const int h    = n & 15;
    const int mb   = n & 3;                     // mask tiling bug preserved

    const int t  = threadIdx.x;
    const int w  = t >> 6;                      // 0..7
    const int wq = w & 3;                       // q-row group
    const int half = w >> 2;                    // key half: 0 -> kt 0..15, 1 -> kt 16..31
    const int l  = t & 63;
    const int G  = l >> 4;
    const int li = l & 15;
    const int G4 = G * 4;
    const int G4p16 = G4 + 16;

    // ---- stage Q (x * pQ * C2 -> bf16): wave w stages rows w*32..w*32+31 ----
    const float C2 = 0.0450842200277800f;
    const float* xb = xin + (size_t)b * Sn * Dn + h * DHn;
    const float pq_s = pQ[h * DHn + l] * C2;
    #pragma unroll 4
    for (int j = 0; j < 32; ++j) {
        float v = xb[(size_t)(q0 + w * 32 + j) * Dn + l];
        S[(w * 32 + j) * STR + l] = f2bf(v * pq_s);
    }
    __syncthreads();                            // cross-wave Q sharing
    short8 qf[4][2];
    #pragma unroll
    for (int qs = 0; qs < 4; ++qs)
        #pragma unroll
        for (int kk = 0; kk < 2; ++kk)
            qf[qs][kk] = *(const short8*)&S[(wq*64 + qs*16 + li) * STR + kk*32 + G*8];
    __syncthreads();                            // Q reads done before dbuf overwrites

    const f32x4 Z4 = {0.f, 0.f, 0.f, 0.f};
    const short8 VONES = {(short)0x3F80, (short)0x3F80, (short)0x3F80, (short)0x3F80,
                          (short)0x3F80, (short)0x3F80, (short)0x3F80, (short)0x3F80};

    f32x4 acc_o[4][4];
    f32x4 acc_l[4];
    #pragma unroll
    for (int qs = 0; qs < 4; ++qs) {
        #pragma unroll
        for (int dg = 0; dg < 4; ++dg) acc_o[qs][dg] = (f32x4){0.f, 0.f, 0.f, 0.f};
        acc_l[qs] = (f32x4){0.f, 0.f, 0.f, 0.f};
    }

    // fragment pointers: wave stages frags wq*2, wq*2+1 of its half's tiles
    const ushort* kwf = Kw + (size_t)n * 131072 + (size_t)(half * 16) * 4096 + (wq * 2) * 512 + (size_t)l * 8;
    const ushort* vwf = Vw + (size_t)n * 131072 + (size_t)(half * 16) * 4096 + (wq * 2) * 512 + (size_t)l * 8;
    const int sbase = half * 16384;             // this half's LDS stream
    const int fo0 = wq * 1024 + l * 8;          // frag slots within a buffer
    const int fo1 = fo0 + 512;

    // masks: row = q0 + wq*64 + li; kt_eff = half*16 + it
    const unsigned long long* mbase = mpack + (size_t)(mb * 2048 + q0 + wq * 64 + li) * 32 + half * 16;

    unsigned long long mA[4], mB[4];

    // ---- prologue: stage this half's tile 0 into buf0, masks it=0 ----
    {
        short8 a = *(const short8*)kwf;
        short8 c = *(const short8*)(kwf + 512);
        short8 d = *(const short8*)vwf;
        short8 e = *(const short8*)(vwf + 512);
        #pragma unroll
        for (int qs = 0; qs < 4; ++qs) mA[qs] = mbase[qs * 512];
        *(short8*)&S[sbase + fo0] = a;
        *(short8*)&S[sbase + fo1] = c;
        *(short8*)&S[sbase + 8192 + fo0] = d;
        *(short8*)&S[sbase + 8192 + fo1] = e;
    }

#define BODY(CUR, NXT, MC, MN, ITv, PF)                                                \
    {                                                                                  \
        __syncthreads();                                                               \
        short8 kst0, kst1, vst0, vst1;                                                 \
        if (PF) {                                                                      \
            const ushort* kp = kwf + (size_t)((ITv)+1) * 4096;                         \
            const ushort* vp = vwf + (size_t)((ITv)+1) * 4096;                         \
            kst0 = *(const short8*)kp;  kst1 = *(const short8*)(kp + 512);             \
            vst0 = *(const short8*)vp;  vst1 = *(const short8*)(vp + 512);             \
            _Pragma("unroll")                                                          \
            for (int qs = 0; qs < 4; ++qs) MN[qs] = mbase[qs * 512 + (ITv) + 1];       \
        }                                                                              \
        /* ---- QK^T (swapped): kf read once, used by 4 qs ---- */                     \
        f32x4 s_[4][4];                                                                \
        _Pragma("unroll")                                                              \
        for (int kg = 0; kg < 4; ++kg) {                                               \
            short8 kf0 = *(const short8*)&S[sbase + (CUR)*4096 + (kg*2+0)*512 + l*8];  \
            short8 kf1 = *(const short8*)&S[sbase + (CUR)*4096 + (kg*2+1)*512 + l*8];  \
            _Pragma("unroll")                                                          \
            for (int qs = 0; qs < 4; ++qs) {                                           \
                s_[qs][kg] = __builtin_amdgcn_mfma_f32_16x16x32_bf16(kf0, qf[qs][0], Z4, 0, 0, 0); \
                s_[qs][kg] = __builtin_amdgcn_mfma_f32_16x16x32_bf16(kf1, qf[qs][1], s_[qs][kg], 0, 0, 0); \
            }                                                                          \
        }                                                                              \
        /* ---- mask + exp + pack ---- */                                              \
        short8 pf[4][2];                                                               \
        _Pragma("unroll")                                                              \
        for (int qs = 0; qs < 4; ++qs) {                                               \
            unsigned mlo = (unsigned)(MC[qs]);                                         \
            unsigned mhi = (unsigned)((MC[qs]) >> 32);                                 \
            float ev[16];                                                              \
            _Pragma("unroll")                                                          \
            for (int kg = 0; kg < 4; ++kg) {                                           \
                unsigned dwh = (kg < 2) ? mlo : mhi;                                   \
                unsigned nib;                                                          \
                asm("v_bfe_u32 %0, %1, %2, 4" : "=v"(nib)                              \
                    : "v"(dwh), "v"((kg & 1) ? G4p16 : G4));                           \
                _Pragma("unroll")                                                      \
                for (int r = 0; r < 4; ++r)                                            \
                    ev[kg*4 + r] = fexp2(mask_sel(nib, r, s_[qs][kg][r]));             \
            }                                                                          \
            _Pragma("unroll")                                                          \
            for (int hh = 0; hh < 2; ++hh) {                                           \
                union { unsigned u[4]; short8 v; } pu;                                 \
                pu.u[0] = pack_bf2(ev[hh*8+0], ev[hh*8+1]);                            \
                pu.u[1] = pack_bf2(ev[hh*8+2], ev[hh*8+3]);                            \
                pu.u[2] = pack_bf2(ev[hh*8+4], ev[hh*8+5]);                            \
                pu.u[3] = pack_bf2(ev[hh*8+6], ev[hh*8+7]);                            \
                pf[qs][hh] = pu.v;                                                     \
            }                                                                          \
        }                                                                              \
        /* ---- PV + lsum ---- */                                                      \
        _Pragma("unroll")                                                              \
        for (int hh = 0; hh < 2; ++hh) {                                               \
            short8 vf0 = *(const short8*)&S[sbase + 8192 + (CUR)*4096 + (hh*4+0)*512 + l*8]; \
            short8 vf1 = *(const short8*)&S[sbase + 8192 + (CUR)*4096 + (hh*4+1)*512 + l*8]; \
            short8 vf2 = *(const short8*)&S[sbase + 8192 + (CUR)*4096 + (hh*4+2)*512 + l*8]; \
            short8 vf3 = *(const short8*)&S[sbase + 8192 + (CUR)*4096 + (hh*4+3)*512 + l*8]; \
            _Pragma("unroll")                                                          \
            for (int qs = 0; qs < 4; ++qs) {                                           \
                acc_o[qs][0] = __builtin_amdgcn_mfma_f32_16x16x32_bf16(pf[qs][hh], vf0, acc_o[qs][0], 0, 0, 0); \
                acc_o[qs][1] = __builtin_amdgcn_mfma_f32_16x16x32_bf16(pf[qs][hh], vf1, acc_o[qs][1], 0, 0, 0); \
                acc_o[qs][2] = __builtin_amdgcn_mfma_f32_16x16x32_bf16(pf[qs][hh], vf2, acc_o[qs][2], 0, 0, 0); \
                acc_o[qs][3] = __builtin_amdgcn_mfma_f32_16x16x32_bf16(pf[qs][hh], vf3, acc_o[qs][3], 0, 0, 0); \
                acc_l[qs]    = __builtin_amdgcn_mfma_f32_16x16x32_bf16(pf[qs][hh], VONES, acc_l[qs], 0, 0, 0); \
            }                                                                          \
        }                                                                              \
        if (PF) {                                                                      \
            *(short8*)&S[sbase + (NXT)*4096 + fo0] = kst0;                             \
            *(short8*)&S[sbase + (NXT)*4096 + fo1] = kst1;                             \
            *(short8*)&S[sbase + 8192 + (NXT)*4096 + fo0] = vst0;                      \
            *(short8*)&S[sbase + 8192 + (NXT)*4096 + fo1] = vst1;                      \
        }                                                                              \
    }

    for (int it = 0; it < 16; it += 2) {
        BODY(0, 1, mA, mB, it, true)
        BODY(1, 0, mB, mA, it + 1, (it + 1 < 15))
    }
#undef BODY

    // ---- combine wave pairs (w, w+4): additive partials (fixed max=0) ----
    float* Sf = (float*)S;
    #pragma unroll
    for (int qs = 0; qs < 4; ++qs) {
        __syncthreads();
        if (half == 1) {
            float* dst = Sf + (wq * 64 + l) * 20;
            *(f32x4*)(dst +  0) = acc_o[qs][0];
            *(f32x4*)(dst +  4) = acc_o[qs][1];
            *(f32x4*)(dst +  8) = acc_o[qs][2];
            *(f32x4*)(dst + 12) = acc_o[qs][3];
            *(f32x4*)(dst + 16) = acc_l[qs];
        }
        __syncthreads();
        if (half == 0) {
            const float* src = Sf + (wq * 64 + l) * 20;
            f32x4 a0 = *(const f32x4*)(src +  0);
            f32x4 a1 = *(const f32x4*)(src +  4);
            f32x4 a2 = *(const f32x4*)(src +  8);
            f32x4 a3 = *(const f32x4*)(src + 12);
            f32x4 al = *(const f32x4*)(src + 16);
            acc_o[qs][0] += a0; acc_o[qs][1] += a1;
            acc_o[qs][2] += a2; acc_o[qs][3] += a3;
            acc_l[qs] += al;
        }
    }

    // ---- epilogue (waves 0-3): ctx = O / l ----
    if (half == 0) {
        #pragma unroll
        for (int qs = 0; qs < 4; ++qs) {
            #pragma unroll
            for (int r = 0; r < 4; ++r) {
                float inv = 1.f / acc_l[qs][r];
                int qg = q0 + wq*64 + qs*16 + G4 + r;
                float* ob = out + ((size_t)b * Sn + qg) * Dn + h * DHn;
                #pragma unroll
                for (int dg = 0; dg < 4; ++dg)
                    ob[dg*16 + li] = acc_o[qs][dg][r] * inv;
            }
        }
    }
}

// ============ fallback prep (round-7 layout) ============
__global__ __launch_bounds__(256)
void prep_kv(const float* __restrict__ xin, const float* __restrict__ pK,
             const float* __restrict__ pV, ushort* __restrict__ Kbf,
             ushort* __restrict__ Vtw)
{
    __shared__ ushort Ls[64 * STR];
    const int n = blockIdx.y, b = n >> 4, h = n & 15;
    const int s0 = blockIdx.x * 64;
    const int t = threadIdx.x;
    const int sl = t >> 2, dq = (t & 3) * 16;

    const float* xp = xin + (size_t)b * Sn * Dn + (size_t)(s0 + sl) * Dn + h * DHn + dq;
    const float* pkp = pK + h * DHn + dq;
    const float* pvp = pV + h * DHn + dq;

    float xv[16], pk[16], pv[16];
    #pragma unroll
    for (int j = 0; j < 4; ++j) {
        float4 a = ((const float4*)xp)[j];
        float4 kk = ((const float4*)pkp)[j];
        float4 vv = ((const float4*)pvp)[j];
        xv[4*j+0] = a.x;  xv[4*j+1] = a.y;  xv[4*j+2] = a.z;  xv[4*j+3] = a.w;
        pk[4*j+0] = kk.x; pk[4*j+1] = kk.y; pk[4*j+2] = kk.z; pk[4*j+3] = kk.w;
        pv[4*j+0] = vv.x; pv[4*j+1] = vv.y; pv[4*j+2] = vv.z; pv[4*j+3] = vv.w;
    }
    unsigned kw[8], vw[8];
    #pragma unroll
    for (int j = 0; j < 8; ++j) {
        kw[j] = pack_bf2(xv[2*j] * pk[2*j], xv[2*j+1] * pk[2*j+1]);
        vw[j] = pack_bf2(xv[2*j] * pv[2*j], xv[2*j+1] * pv[2*j+1]);
    }
    ushort* kdst = Kbf + ((size_t)n * Sn + s0 + sl) * DHn + dq;
    *(uint4*)kdst       = make_uint4(kw[0], kw[1], kw[2], kw[3]);
    *(uint4*)(kdst + 8) = make_uint4(kw[4], kw[5], kw[6], kw[7]);

    *(uint4*)&Ls[sl * STR + dq]     = make_uint4(vw[0], vw[1], vw[2], vw[3]);
    *(uint4*)&Ls[sl * STR + dq + 8] = make_uint4(vw[4], vw[5], vw[6], vw[7]);
    __syncthreads();

    const int dh = t >> 2, p4 = t & 3;
    ushort ov[16];
    #pragma unroll
    for (int j = 0; j < 16; ++j) {
        int p  = p4 * 16 + j;
        int ss = (p & 32) | ((p & 4) << 2) | ((p & 24) >> 1) | (p & 3);
        ov[j] = Ls[ss * STR + dh];
    }
    unsigned ow[8];
    #pragma unroll
    for (int j = 0; j < 8; ++j) ow[j] = (unsigned)ov[2*j] | ((unsigned)ov[2*j+1] << 16);
    ushort* vdst = Vtw + ((size_t)n * DHn + dh) * Sn + s0 + p4 * 16;
    *(uint4*)vdst       = make_uint4(ow[0], ow[1], ow[2], ow[3]);
    *(uint4*)(vdst + 8) = make_uint4(ow[4], ow[5], ow[6], ow[7]);
}

// ============ fallback attention (round-7 verified) ============
__global__ __launch_bounds__(256, 4)
void attn_fast2(const float* __restrict__ xin, const int* __restrict__ masks,
                const float* __restrict__ pQ, const ushort* __restrict__ Kbf,
                const ushort* __restrict__ Vtw, float* __restrict__ out)
{
    __shared__ ushort Ks[KT * STR];
    __shared__ ushort Vts[DHn * STR];

    const int n  = blockIdx.y;
    const int b  = n >> 4;
    const int h  = n & 15;
    const int mb = n & 3;
    const int q0 = blockIdx.x * 128;

    const int t  = threadIdx.x;
    const int w  = t >> 6;
    const int l  = t & 63;
    const int G  = l >> 4;
    const int li = l & 15;

    const float C2 = 0.0450842200277800f;
    const float* xb = xin + (size_t)b * Sn * Dn + h * DHn;
    const float pq_s = pQ[h * DHn + l] * C2;
    ushort* qstage = ((w < 2) ? Ks : Vts) + (w & 1) * (32 * STR);
    #pragma unroll
    for (int i = 0; i < 8; ++i) {
        #pragma unroll
        for (int j = 0; j < 4; ++j) {
            int qr = i * 4 + j;
            float v = xb[(size_t)(q0 + w * 32 + qr) * Dn + l];
            qstage[qr * STR + l] = f2bf(v * pq_s);
        }
    }
    short8 qf[2][2];
    #pragma unroll
    for (int qs = 0; qs < 2; ++qs)
        #pragma unroll
        for (int kk = 0; kk < 2; ++kk)
            qf[qs][kk] = *(const short8*)&qstage[(qs*16 + li) * STR + kk*32 + G*8];

    f32x4 acc_o[2][4];
    float lsum[2];
    #pragma unroll
    for (int qs = 0; qs < 2; ++qs) {
        #pragma unroll
        for (int dg = 0; dg < 4; ++dg) acc_o[qs][dg] = (f32x4){0.f, 0.f, 0.f, 0.f};
        lsum[qs] = 0.f;
    }

    const int* mq = masks + (size_t)mb * Sn * Sn + (size_t)(q0 + w*32 + li) * Sn;

    const int srow = w * 16 + (l >> 2);
    const int part = (l & 3) * 16;
    const ushort* ksrc = Kbf + (size_t)n * Sn * DHn + (size_t)srow * DHn + part;
    const ushort* vsrc = Vtw + (size_t)n * DHn * Sn + (size_t)srow * Sn + part;
    ushort* kdst = &Ks[srow * STR + part];
    ushort* vdst = &Vts[srow * STR + part];

    for (int kt = 0; kt < Sn / KT; ++kt) {
        __syncthreads();
        const ushort* kp = ksrc + (size_t)kt * KT * DHn;
        const ushort* vp = vsrc + kt * KT;
        short8 k0 = *(const short8*)kp, k1 = *(const short8*)(kp + 8);
        short8 v0 = *(const short8*)vp, v1 = *(const short8*)(vp + 8);
        *(short8*)kdst       = k0;
        *(short8*)(kdst + 8) = k1;
        *(short8*)vdst       = v0;
        *(short8*)(vdst + 8) = v1;
        __syncthreads();

        f32x4 s[2][4];
        #pragma unroll
        for (int qs = 0; qs < 2; ++qs)
            #pragma unroll
            for (int kg = 0; kg < 4; ++kg) s[qs][kg] = (f32x4){0.f, 0.f, 0.f, 0.f};
        #pragma unroll
        for (int kg = 0; kg < 4; ++kg) {
            #pragma unroll
            for (int kk = 0; kk < 2; ++kk) {
                short8 kf = *(const short8*)&Ks[(kg*16 + li) * STR + kk*32 + G*8];
                s[0][kg] = __builtin_amdgcn_mfma_f32_16x16x32_bf16(kf, qf[0][kk], s[0][kg], 0, 0, 0);
                s[1][kg] = __builtin_amdgcn_mfma_f32_16x16x32_bf16(kf, qf[1][kk], s[1][kg], 0, 0, 0);
            }
        }

        short8 pf[2][2];
        #pragma unroll
        for (int qs = 0; qs < 2; ++qs) {
            int4 mv[4];
            #pragma unroll
            for (int kg = 0; kg < 4; ++kg)
                mv[kg] = *(const int4*)(mq + (size_t)qs*16*Sn + kt*KT + kg*16 + G*4);
            float ev[16];
            #pragma unroll
            for (int kg = 0; kg < 4; ++kg) {
                int ma[4] = {mv[kg].x, mv[kg].y, mv[kg].z, mv[kg].w};
                #pragma unroll
                for (int r = 0; r < 4; ++r) {
                    float tt = ma[r] ? 0.f : s[qs][kg][r];
                    ev[kg*4 + r] = fexp2(tt);
                }
            }
            lsum[qs] += (((ev[0]+ev[1])+(ev[2]+ev[3])) + ((ev[4]+ev[5])+(ev[6]+ev[7])))
                      + (((ev[8]+ev[9])+(ev[10]+ev[11])) + ((ev[12]+ev[13])+(ev[14]+ev[15])));
            #pragma unroll
            for (int hh = 0; hh < 2; ++hh) {
                union { unsigned u[4]; short8 v; } pu;
                pu.u[0] = pack_bf2(ev[hh*8+0], ev[hh*8+1]);
                pu.u[1] = pack_bf2(ev[hh*8+2], ev[hh*8+3]);
                pu.u[2] = pack_bf2(ev[hh*8+4], ev[hh*8+5]);
                pu.u[3] = pack_bf2(ev[hh*8+6], ev[hh*8+7]);
                pf[qs][hh] = pu.v;
            }
        }

        #pragma unroll
        for (int hh = 0; hh < 2; ++hh) {
            short8 vf[4];
            #pragma unroll
            for (int dg = 0; dg < 4; ++dg)
                vf[dg] = *(const short8*)&Vts[(dg*16 + li) * STR + hh*32 + G*8];
            #pragma unroll
            for (int qs = 0; qs < 2; ++qs)
                #pragma unroll
                for (int dg = 0; dg < 4; ++dg)
                    acc_o[qs][dg] = __builtin_amdgcn_mfma_f32_16x16x32_bf16(pf[qs][hh], vf[dg], acc_o[qs][dg], 0, 0, 0);
        }
    }

    #pragma unroll
    for (int qs = 0; qs < 2; ++qs) {
        float v = lsum[qs];
        v += __shfl_xor(v, 16, 64);
        v += __shfl_xor(v, 32, 64);
        lsum[qs] = v;
    }

    #pragma unroll
    for (int qs = 0; qs < 2; ++qs) {
        #pragma unroll
        for (int r = 0; r < 4; ++r) {
            float lv = __shfl(lsum[qs], (l & 48) | (G * 4 + r), 64);
            float inv = 1.f / lv;
            int qg = q0 + w*32 + qs*16 + G*4 + r;
            float* ob = out + ((size_t)b * Sn + qg) * Dn + h * DHn;
            #pragma unroll
            for (int dg = 0; dg < 4; ++dg)
                ob[dg*16 + li] = acc_o[qs][dg][r] * inv;
        }
    }
}

// residual + LayerNorm, in-place on d_out
__global__ __launch_bounds__(256)
void ln_kernel(const float* __restrict__ qin, const float* __restrict__ gamma,
               const float* __restrict__ beta, float* __restrict__ out)
{
    const int row = blockIdx.x;
    const int t   = threadIdx.x;
    const size_t base = (size_t)row * Dn + t * 4;

    float4 c = *(const float4*)(out + base);
    float4 r = *(const float4*)(qin + base);
    float4 v = make_float4(c.x + r.x, c.y + r.y, c.z + r.z, c.w + r.w);

    float sum = v.x + v.y + v.z + v.w;
    float sq  = v.x * v.x + v.y * v.y + v.z * v.z + v.w * v.w;
    #pragma unroll
    for (int off = 32; off >= 1; off >>= 1) {
        sum += __shfl_xor(sum, off, 64);
        sq  += __shfl_xor(sq,  off, 64);
    }
    __shared__ float as_[4], aq_[4];
    const int wid = t >> 6, ln = t & 63;
    if (ln == 0) { as_[wid] = sum; aq_[wid] = sq; }
    __syncthreads();
    sum = as_[0] + as_[1] + as_[2] + as_[3];
    sq  = aq_[0] + aq_[1] + aq_[2] + aq_[3];

    const float mean = sum * (1.f / Dn);
    const float var  = sq * (1.f / Dn) - mean * mean;
    const float rstd = rsqrtf(var + 1e-5f);

    float4 ga = *(const float4*)(gamma + t * 4);
    float4 be = *(const float4*)(beta + t * 4);
    float4 o;
    o.x = (v.x - mean) * rstd * ga.x + be.x;
    o.y = (v.y - mean) * rstd * ga.y + be.y;
    o.z = (v.z - mean) * rstd * ga.z + be.z;
    o.w = (v.w - mean) * rstd * ga.w + be.w;
    *(float4*)(out + base) = o;
}

extern "C" void kernel_launch(void* const* d_in, const int* in_sizes, int n_in,
                              void* d_out, int out_size, void* d_ws, size_t ws_size,
                              hipStream_t stream) {
    const float* q     = (const float*)d_in[0];
    // d_in[1] (k), d_in[2] (v) ignored: reference bug preserved
    const int*   masks = (const int*)d_in[3];
    const float* pQ    = (const float*)d_in[4];
    const float* pK    = (const float*)d_in[5];
    const float* pV    = (const float*)d_in[6];
    const float* gamma = (const float*)d_in[7];
    const float* beta  = (const float*)d_in[8];
    float* out = (float*)d_out;
    (void)in_sizes; (void)n_in; (void)out_size;

    const size_t elems = (size_t)Bn * Hn * Sn * DHn;            // 8,388,608
    const size_t kvbytes = elems * 2 * sizeof(ushort);          // 32 MiB
    const size_t need3 = kvbytes + (size_t)4 * Sn * 32 * 8;     // +2 MiB mask bits

    if (ws_size >= need3) {
        ushort* Kw = (ushort*)d_ws;
        ushort* Vw = Kw + elems;
        unsigned long long* mpack = (unsigned long long*)((char*)d_ws + kvbytes);
        prep_fused<<<6144, 256, 0, stream>>>(q, pK, pV, masks, Kw, Vw, mpack);
        attn_fast7<<<512, 512, 0, stream>>>(q, mpack, pQ, Kw, Vw, out);
    } else if (ws_size >= kvbytes) {
        ushort* Kbf = (ushort*)d_ws;
        ushort* Vtw = Kbf + elems;
        prep_kv<<<dim3(Sn / 64, Bn * Hn), 256, 0, stream>>>(q, pK, pV, Kbf, Vtw);
        attn_fast2<<<dim3(Sn / 128, Bn * Hn), 256, 0, stream>>>(q, masks, pQ, Kbf, Vtw, out);
    }
    ln_kernel<<<Bn * Sn, 256, 0, stream>>>(q, gamma, beta, out);
}

// Round 22
// 128.525 us; speedup vs baseline: 1.0832x; 1.0832x over previous
//
#include <hip/hip_runtime.h>
#include <math.h>

#define Bn 4
#define Sn 2048
#define Dn 1024
#define Hn 16
#define DHn 64
#define KT 64            // keys per tile
#define STR 72           // padded ushort stride for row-major scratch

typedef __attribute__((ext_vector_type(8))) short short8;
typedef __attribute__((ext_vector_type(4))) float f32x4;

__device__ __forceinline__ ushort f2bf(float f) {
    union { float f; unsigned u; } x; x.f = f;
    unsigned r = x.u + 0x7fffu + ((x.u >> 16) & 1u);   // RNE
    return (ushort)(r >> 16);
}

__device__ __forceinline__ unsigned pack_bf2(float lo, float hi) {
    unsigned r;
    asm("v_cvt_pk_bf16_f32 %0, %1, %2" : "=v"(r) : "v"(lo), "v"(hi));
    return r;
}

// r12: native v_exp_f32 (libm exp2f = ~15-instr OCML path without fast-math)
__device__ __forceinline__ float fexp2(float x) { return __builtin_amdgcn_exp2f(x); }

// r13: 2-op masked score: sx = sext(bit r of nib); t = bfi(sx, 0, s) = sx ? 0 : s
__device__ __forceinline__ float mask_sel(unsigned nib, int r, float s) {
    int sx; unsigned tb;
    asm("v_bfe_i32 %0, %1, %2, 1" : "=v"(sx) : "v"(nib), "i"(r));
    asm("v_bfi_b32 %0, %1, 0, %2" : "=v"(tb) : "v"(sx), "v"(__float_as_uint(s)));
    return __uint_as_float(tb);
}

// ============ fused prep: blocks [0,2048) build fragment-major K/V; [2048,6144) bitpack masks ============
// Kw[n][kt][f][lane][8]: f = kg*2+kk; lane l holds K[key=kt*64+kg*16+(l&15)][dh=kk*32+(l>>4)*8 ..+7]
// Vw[n][kt][fv][lane][8]: fv = hh*4+dg; lane l holds Vt[dh=dg*16+(l&15)][p=hh*32+(l>>4)*8 ..+7]
//   Vt[dh][p] = V[psi_inv(p)][dh], psi_inv(p) = (p&32)|((p&4)<<2)|((p&24)>>1)|(p&3)
__global__ __launch_bounds__(256)
void prep_fused(const float* __restrict__ xin, const float* __restrict__ pK,
                const float* __restrict__ pV, const int* __restrict__ masks,
                ushort* __restrict__ Kw, ushort* __restrict__ Vw,
                unsigned long long* __restrict__ mpack)
{
    __shared__ ushort LK[64 * STR];
    __shared__ ushort LV[64 * STR];
    const int t = threadIdx.x;

    if (blockIdx.x >= 2048) {                   // ---- mask bitpack role ----
        const int l = t & 63;
        const int wid_g = ((blockIdx.x - 2048) * 256 + t) >> 6;   // 0..16383
        #pragma unroll 4
        for (int i = 0; i < 16; ++i) {
            int word = wid_g * 16 + i;
            int row  = word >> 5, wd = word & 31;
            int m = masks[(size_t)row * 2048 + wd * 64 + l];
            unsigned long long bits = __ballot(m != 0);
            if (l == 0) mpack[word] = bits;
        }
        return;
    }

    const int kt = blockIdx.x & 31, n = blockIdx.x >> 5, b = n >> 4, h = n & 15;
    const int sl = t >> 2, dq = (t & 3) * 16;

    const float* xp  = xin + ((size_t)b * Sn + kt * 64 + sl) * Dn + h * DHn + dq;
    const float* pkp = pK + h * DHn + dq;
    const float* pvp = pV + h * DHn + dq;

    float xv[16], pk[16], pv[16];
    #pragma unroll
    for (int j = 0; j < 4; ++j) {
        float4 a  = ((const float4*)xp)[j];
        float4 kk = ((const float4*)pkp)[j];
        float4 vv = ((const float4*)pvp)[j];
        xv[4*j+0] = a.x;  xv[4*j+1] = a.y;  xv[4*j+2] = a.z;  xv[4*j+3] = a.w;
        pk[4*j+0] = kk.x; pk[4*j+1] = kk.y; pk[4*j+2] = kk.z; pk[4*j+3] = kk.w;
        pv[4*j+0] = vv.x; pv[4*j+1] = vv.y; pv[4*j+2] = vv.z; pv[4*j+3] = vv.w;
    }
    unsigned kw[8], vw[8];
    #pragma unroll
    for (int j = 0; j < 8; ++j) {
        kw[j] = pack_bf2(xv[2*j] * pk[2*j], xv[2*j+1] * pk[2*j+1]);
        vw[j] = pack_bf2(xv[2*j] * pv[2*j], xv[2*j+1] * pv[2*j+1]);
    }
    *(uint4*)&LK[sl * STR + dq]     = make_uint4(kw[0], kw[1], kw[2], kw[3]);
    *(uint4*)&LK[sl * STR + dq + 8] = make_uint4(kw[4], kw[5], kw[6], kw[7]);
    *(uint4*)&LV[sl * STR + dq]     = make_uint4(vw[0], vw[1], vw[2], vw[3]);
    *(uint4*)&LV[sl * STR + dq + 8] = make_uint4(vw[4], vw[5], vw[6], vw[7]);
    __syncthreads();

    ushort* kout = Kw + ((size_t)n * 32 + kt) * 4096;
    ushort* vout = Vw + ((size_t)n * 32 + kt) * 4096;
    #pragma unroll
    for (int i = 0; i < 2; ++i) {
        int c  = t * 2 + i;           // chunk 0..511
        int f  = c >> 6, lc = c & 63;
        int key = (f >> 1) * 16 + (lc & 15);
        int dh0 = (f & 1) * 32 + (lc >> 4) * 8;
        *(uint4*)(kout + c * 8) = *(const uint4*)&LK[key * STR + dh0];
        int dg = f & 3, hh = f >> 2;
        int dhv = dg * 16 + (lc & 15);
        ushort tmp[8];
        #pragma unroll
        for (int e = 0; e < 8; ++e) {
            int p  = hh * 32 + (lc >> 4) * 8 + e;
            int ss = (p & 32) | ((p & 4) << 2) | ((p & 24) >> 1) | (p & 3);
            tmp[e] = LV[ss * STR + dhv];
        }
        unsigned o0 = (unsigned)tmp[0] | ((unsigned)tmp[1] << 16);
        unsigned o1 = (unsigned)tmp[2] | ((unsigned)tmp[3] << 16);
        unsigned o2 = (unsigned)tmp[4] | ((unsigned)tmp[5] << 16);
        unsigned o3 = (unsigned)tmp[6] | ((unsigned)tmp[7] << 16);
        *(uint4*)(vout + c * 8) = make_uint4(o0, o1, o2, o3);
    }
}

// ============ attn6 (r18/r20 verified champion): 64 q-rows/wave, dbuf LDS, 1 barrier/tile ============
// r21 post-mortem: split-K with corrected (512,2) bounds ran clean (VGPR 128, no
// spill) but LOST: 106 vs 96us. 64KB LDS still caps 2 blocks/CU; barriers now
// lockstep 8 waves instead of 4; combine adds overhead. Occupancy lever closed
// from every direction (grid, LDS, VGPR, barrier-free x2, reg-dbuf). Champion
// restored: attn 96us, total ~128.6us (verified r18, r20).
__global__ __launch_bounds__(256, 2)
void attn_fast6(const float* __restrict__ xin, const unsigned long long* __restrict__ mpack,
                const float* __restrict__ pQ, const ushort* __restrict__ Kw,
                const ushort* __restrict__ Vw, float* __restrict__ out)
{
    // S: Q scratch 256 rows x STR (36.9 KB); after barrier, first 32 KB = K/V dbuf
    // Kbuf0 [0,4096), Kbuf1 [4096,8192), Vbuf0 [8192,12288), Vbuf1 [12288,16384) (ushort idx)
    __shared__ __attribute__((aligned(16))) ushort S[256 * STR];

    const int id   = blockIdx.x;
    const int xcd  = id & 7, pos = id >> 3;     // 512 blocks: pos 0..63
    const int n    = (pos >> 3) * 8 + xcd;      // head-locality per XCD
    const int q0   = (pos & 7) * 256;
    const int b    = n >> 4;
    const int h    = n & 15;
    const int mb   = n & 3;                     // mask tiling bug preserved

    const int t  = threadIdx.x;
    const int w  = t >> 6;
    const int l  = t & 63;
    const int G  = l >> 4;
    const int li = l & 15;
    const int G4 = G * 4;
    const int G4p16 = G4 + 16;

    // ---- stage Q (x * pQ * C2 -> bf16): wave w rows w*64 .. w*64+63 ----
    const float C2 = 0.0450842200277800f;       // (1/32)*log2(e) folded into Q
    const float* xb = xin + (size_t)b * Sn * Dn + h * DHn;
    const float pq_s = pQ[h * DHn + l] * C2;
    #pragma unroll 4
    for (int j = 0; j < 64; ++j) {
        float v = xb[(size_t)(q0 + w * 64 + j) * Dn + l];
        S[(w * 64 + j) * STR + l] = f2bf(v * pq_s);
    }
    short8 qf[4][2];
    #pragma unroll
    for (int qs = 0; qs < 4; ++qs)
        #pragma unroll
        for (int kk = 0; kk < 2; ++kk)
            qf[qs][kk] = *(const short8*)&S[(w*64 + qs*16 + li) * STR + kk*32 + G*8];
    __syncthreads();   // all waves done reading Q before dbuf overwrites S

    const f32x4 Z4 = {0.f, 0.f, 0.f, 0.f};
    const short8 VONES = {(short)0x3F80, (short)0x3F80, (short)0x3F80, (short)0x3F80,
                          (short)0x3F80, (short)0x3F80, (short)0x3F80, (short)0x3F80};

    f32x4 acc_o[4][4];
    f32x4 acc_l[4];
    #pragma unroll
    for (int qs = 0; qs < 4; ++qs) {
        #pragma unroll
        for (int dg = 0; dg < 4; ++dg) acc_o[qs][dg] = (f32x4){0.f, 0.f, 0.f, 0.f};
        acc_l[qs] = (f32x4){0.f, 0.f, 0.f, 0.f};
    }

    // per-thread fragment pointers (wave w stages frags w*2, w*2+1)
    const ushort* kwf = Kw + (size_t)n * 131072 + (w * 2) * 512 + (size_t)l * 8;
    const ushort* vwf = Vw + (size_t)n * 131072 + (w * 2) * 512 + (size_t)l * 8;
    const int fo0 = (w * 2) * 512 + l * 8;
    const int fo1 = (w * 2 + 1) * 512 + l * 8;

    // mask base: row = q0 + w*64 + li; qs adds 16 rows = 512 u64
    const unsigned long long* mbase = mpack + (size_t)(mb * 2048 + q0 + w * 64 + li) * 32;

    unsigned long long mA[4], mB[4];

    // ---- prologue: stage tile 0 into buf0, masks for kt=0 ----
    {
        short8 a = *(const short8*)kwf;
        short8 c = *(const short8*)(kwf + 512);
        short8 d = *(const short8*)vwf;
        short8 e = *(const short8*)(vwf + 512);
        #pragma unroll
        for (int qs = 0; qs < 4; ++qs) mA[qs] = mbase[qs * 512];
        *(short8*)&S[fo0] = a;
        *(short8*)&S[fo1] = c;
        *(short8*)&S[8192 + fo0] = d;
        *(short8*)&S[8192 + fo1] = e;
    }

#define BODY(CUR, NXT, MC, MN, KTv, PF)                                                \
    {                                                                                  \
        __syncthreads();  /* buf CUR published; buf NXT readers done */                \
        /* ---- issue next-tile loads first (full-iteration latency cover) ---- */     \
        short8 kst0, kst1, vst0, vst1;                                                 \
        if (PF) {                                                                      \
            const ushort* kp = kwf + (size_t)((KTv)+1) * 4096;                         \
            const ushort* vp = vwf + (size_t)((KTv)+1) * 4096;                         \
            kst0 = *(const short8*)kp;  kst1 = *(const short8*)(kp + 512);             \
            vst0 = *(const short8*)vp;  vst1 = *(const short8*)(vp + 512);             \
            _Pragma("unroll")                                                          \
            for (int qs = 0; qs < 4; ++qs) MN[qs] = mbase[qs * 512 + (KTv) + 1];       \
        }                                                                              \
        /* ---- QK^T (swapped): kf read ONCE, used by all 4 qs ---- */                 \
        f32x4 s_[4][4];                                                                \
        _Pragma("unroll")                                                              \
        for (int kg = 0; kg < 4; ++kg) {                                               \
            short8 kf0 = *(const short8*)&S[(CUR)*4096 + (kg*2+0)*512 + l*8];          \
            short8 kf1 = *(const short8*)&S[(CUR)*4096 + (kg*2+1)*512 + l*8];          \
            _Pragma("unroll")                                                          \
            for (int qs = 0; qs < 4; ++qs) {                                           \
                s_[qs][kg] = __builtin_amdgcn_mfma_f32_16x16x32_bf16(kf0, qf[qs][0], Z4, 0, 0, 0); \
                s_[qs][kg] = __builtin_amdgcn_mfma_f32_16x16x32_bf16(kf1, qf[qs][1], s_[qs][kg], 0, 0, 0); \
            }                                                                          \
        }                                                                              \
        /* ---- mask (bfe/bfi) + native exp + in-register P pack ---- */               \
        short8 pf[4][2];                                                               \
        _Pragma("unroll")                                                              \
        for (int qs = 0; qs < 4; ++qs) {                                               \
            unsigned mlo = (unsigned)(MC[qs]);                                         \
            unsigned mhi = (unsigned)((MC[qs]) >> 32);                                 \
            float ev[16];                                                              \
            _Pragma("unroll")                                                          \
            for (int kg = 0; kg < 4; ++kg) {                                           \
                unsigned dwh = (kg < 2) ? mlo : mhi;                                   \
                unsigned nib;                                                          \
                asm("v_bfe_u32 %0, %1, %2, 4" : "=v"(nib)                              \
                    : "v"(dwh), "v"((kg & 1) ? G4p16 : G4));                           \
                _Pragma("unroll")                                                      \
                for (int r = 0; r < 4; ++r)                                            \
                    ev[kg*4 + r] = fexp2(mask_sel(nib, r, s_[qs][kg][r]));             \
            }                                                                          \
            _Pragma("unroll")                                                          \
            for (int hh = 0; hh < 2; ++hh) {                                           \
                union { unsigned u[4]; short8 v; } pu;                                 \
                pu.u[0] = pack_bf2(ev[hh*8+0], ev[hh*8+1]);                            \
                pu.u[1] = pack_bf2(ev[hh*8+2], ev[hh*8+3]);                            \
                pu.u[2] = pack_bf2(ev[hh*8+4], ev[hh*8+5]);                            \
                pu.u[3] = pack_bf2(ev[hh*8+6], ev[hh*8+7]);                            \
                pf[qs][hh] = pu.v;                                                     \
            }                                                                          \
        }                                                                              \
        /* ---- PV + lsum: vf read ONCE, used by all 4 qs ---- */                      \
        _Pragma("unroll")                                                              \
        for (int hh = 0; hh < 2; ++hh) {                                               \
            short8 vf0 = *(const short8*)&S[8192 + (CUR)*4096 + (hh*4+0)*512 + l*8];   \
            short8 vf1 = *(const short8*)&S[8192 + (CUR)*4096 + (hh*4+1)*512 + l*8];   \
            short8 vf2 = *(const short8*)&S[8192 + (CUR)*4096 + (hh*4+2)*512 + l*8];   \
            short8 vf3 = *(const short8*)&S[8192 + (CUR)*4096 + (hh*4+3)*512 + l*8];   \
            _Pragma("unroll")                                                          \
            for (int qs = 0; qs < 4; ++qs) {                                           \
                acc_o[qs][0] = __builtin_amdgcn_mfma_f32_16x16x32_bf16(pf[qs][hh], vf0, acc_o[qs][0], 0, 0, 0); \
                acc_o[qs][1] = __builtin_amdgcn_mfma_f32_16x16x32_bf16(pf[qs][hh], vf1, acc_o[qs][1], 0, 0, 0); \
                acc_o[qs][2] = __builtin_amdgcn_mfma_f32_16x16x32_bf16(pf[qs][hh], vf2, acc_o[qs][2], 0, 0, 0); \
                acc_o[qs][3] = __builtin_amdgcn_mfma_f32_16x16x32_bf16(pf[qs][hh], vf3, acc_o[qs][3], 0, 0, 0); \
                acc_l[qs]    = __builtin_amdgcn_mfma_f32_16x16x32_bf16(pf[qs][hh], VONES, acc_l[qs], 0, 0, 0); \
            }                                                                          \
        }                                                                              \
        /* ---- write staged regs into next buffer ---- */                             \
        if (PF) {                                                                      \
            *(short8*)&S[(NXT)*4096 + fo0] = kst0;                                     \
            *(short8*)&S[(NXT)*4096 + fo1] = kst1;                                     \
            *(short8*)&S[8192 + (NXT)*4096 + fo0] = vst0;                              \
            *(short8*)&S[8192 + (NXT)*4096 + fo1] = vst1;                              \
        }                                                                              \
    }

    for (int kt = 0; kt < 32; kt += 2) {
        BODY(0, 1, mA, mB, kt, true)
        BODY(1, 0, mB, mA, kt + 1, (kt + 1 < 31))
    }
#undef BODY

    // ---- epilogue: ctx = O / l ; acc_l row-mapping matches acc_o ----
    #pragma unroll
    for (int qs = 0; qs < 4; ++qs) {
        #pragma unroll
        for (int r = 0; r < 4; ++r) {
            float inv = 1.f / acc_l[qs][r];
            int qg = q0 + w*64 + qs*16 + G4 + r;
            float* ob = out + ((size_t)b * Sn + qg) * Dn + h * DHn;
            #pragma unroll
            for (int dg = 0; dg < 4; ++dg)
                ob[dg*16 + li] = acc_o[qs][dg][r] * inv;
        }
    }
}

// ============ fallback prep (round-7 layout) ============
__global__ __launch_bounds__(256)
void prep_kv(const float* __restrict__ xin, const float* __restrict__ pK,
             const float* __restrict__ pV, ushort* __restrict__ Kbf,
             ushort* __restrict__ Vtw)
{
    __shared__ ushort Ls[64 * STR];
    const int n = blockIdx.y, b = n >> 4, h = n & 15;
    const int s0 = blockIdx.x * 64;
    const int t = threadIdx.x;
    const int sl = t >> 2, dq = (t & 3) * 16;

    const float* xp = xin + (size_t)b * Sn * Dn + (size_t)(s0 + sl) * Dn + h * DHn + dq;
    const float* pkp = pK + h * DHn + dq;
    const float* pvp = pV + h * DHn + dq;

    float xv[16], pk[16], pv[16];
    #pragma unroll
    for (int j = 0; j < 4; ++j) {
        float4 a = ((const float4*)xp)[j];
        float4 kk = ((const float4*)pkp)[j];
        float4 vv = ((const float4*)pvp)[j];
        xv[4*j+0] = a.x;  xv[4*j+1] = a.y;  xv[4*j+2] = a.z;  xv[4*j+3] = a.w;
        pk[4*j+0] = kk.x; pk[4*j+1] = kk.y; pk[4*j+2] = kk.z; pk[4*j+3] = kk.w;
        pv[4*j+0] = vv.x; pv[4*j+1] = vv.y; pv[4*j+2] = vv.z; pv[4*j+3] = vv.w;
    }
    unsigned kw[8], vw[8];
    #pragma unroll
    for (int j = 0; j < 8; ++j) {
        kw[j] = pack_bf2(xv[2*j] * pk[2*j], xv[2*j+1] * pk[2*j+1]);
        vw[j] = pack_bf2(xv[2*j] * pv[2*j], xv[2*j+1] * pv[2*j+1]);
    }
    ushort* kdst = Kbf + ((size_t)n * Sn + s0 + sl) * DHn + dq;
    *(uint4*)kdst       = make_uint4(kw[0], kw[1], kw[2], kw[3]);
    *(uint4*)(kdst + 8) = make_uint4(kw[4], kw[5], kw[6], kw[7]);

    *(uint4*)&Ls[sl * STR + dq]     = make_uint4(vw[0], vw[1], vw[2], vw[3]);
    *(uint4*)&Ls[sl * STR + dq + 8] = make_uint4(vw[4], vw[5], vw[6], vw[7]);
    __syncthreads();

    const int dh = t >> 2, p4 = t & 3;
    ushort ov[16];
    #pragma unroll
    for (int j = 0; j < 16; ++j) {
        int p  = p4 * 16 + j;
        int ss = (p & 32) | ((p & 4) << 2) | ((p & 24) >> 1) | (p & 3);
        ov[j] = Ls[ss * STR + dh];
    }
    unsigned ow[8];
    #pragma unroll
    for (int j = 0; j < 8; ++j) ow[j] = (unsigned)ov[2*j] | ((unsigned)ov[2*j+1] << 16);
    ushort* vdst = Vtw + ((size_t)n * DHn + dh) * Sn + s0 + p4 * 16;
    *(uint4*)vdst       = make_uint4(ow[0], ow[1], ow[2], ow[3]);
    *(uint4*)(vdst + 8) = make_uint4(ow[4], ow[5], ow[6], ow[7]);
}

// ============ fallback attention (round-7 verified) ============
__global__ __launch_bounds__(256, 4)
void attn_fast2(const float* __restrict__ xin, const int* __restrict__ masks,
                const float* __restrict__ pQ, const ushort* __restrict__ Kbf,
                const ushort* __restrict__ Vtw, float* __restrict__ out)
{
    __shared__ ushort Ks[KT * STR];
    __shared__ ushort Vts[DHn * STR];

    const int n  = blockIdx.y;
    const int b  = n >> 4;
    const int h  = n & 15;
    const int mb = n & 3;
    const int q0 = blockIdx.x * 128;

    const int t  = threadIdx.x;
    const int w  = t >> 6;
    const int l  = t & 63;
    const int G  = l >> 4;
    const int li = l & 15;

    const float C2 = 0.0450842200277800f;
    const float* xb = xin + (size_t)b * Sn * Dn + h * DHn;
    const float pq_s = pQ[h * DHn + l] * C2;
    ushort* qstage = ((w < 2) ? Ks : Vts) + (w & 1) * (32 * STR);
    #pragma unroll
    for (int i = 0; i < 8; ++i) {
        #pragma unroll
        for (int j = 0; j < 4; ++j) {
            int qr = i * 4 + j;
            float v = xb[(size_t)(q0 + w * 32 + qr) * Dn + l];
            qstage[qr * STR + l] = f2bf(v * pq_s);
        }
    }
    short8 qf[2][2];
    #pragma unroll
    for (int qs = 0; qs < 2; ++qs)
        #pragma unroll
        for (int kk = 0; kk < 2; ++kk)
            qf[qs][kk] = *(const short8*)&qstage[(qs*16 + li) * STR + kk*32 + G*8];

    f32x4 acc_o[2][4];
    float lsum[2];
    #pragma unroll
    for (int qs = 0; qs < 2; ++qs) {
        #pragma unroll
        for (int dg = 0; dg < 4; ++dg) acc_o[qs][dg] = (f32x4){0.f, 0.f, 0.f, 0.f};
        lsum[qs] = 0.f;
    }

    const int* mq = masks + (size_t)mb * Sn * Sn + (size_t)(q0 + w*32 + li) * Sn;

    const int srow = w * 16 + (l >> 2);
    const int part = (l & 3) * 16;
    const ushort* ksrc = Kbf + (size_t)n * Sn * DHn + (size_t)srow * DHn + part;
    const ushort* vsrc = Vtw + (size_t)n * DHn * Sn + (size_t)srow * Sn + part;
    ushort* kdst = &Ks[srow * STR + part];
    ushort* vdst = &Vts[srow * STR + part];

    for (int kt = 0; kt < Sn / KT; ++kt) {
        __syncthreads();
        const ushort* kp = ksrc + (size_t)kt * KT * DHn;
        const ushort* vp = vsrc + kt * KT;
        short8 k0 = *(const short8*)kp, k1 = *(const short8*)(kp + 8);
        short8 v0 = *(const short8*)vp, v1 = *(const short8*)(vp + 8);
        *(short8*)kdst       = k0;
        *(short8*)(kdst + 8) = k1;
        *(short8*)vdst       = v0;
        *(short8*)(vdst + 8) = v1;
        __syncthreads();

        f32x4 s[2][4];
        #pragma unroll
        for (int qs = 0; qs < 2; ++qs)
            #pragma unroll
            for (int kg = 0; kg < 4; ++kg) s[qs][kg] = (f32x4){0.f, 0.f, 0.f, 0.f};
        #pragma unroll
        for (int kg = 0; kg < 4; ++kg) {
            #pragma unroll
            for (int kk = 0; kk < 2; ++kk) {
                short8 kf = *(const short8*)&Ks[(kg*16 + li) * STR + kk*32 + G*8];
                s[0][kg] = __builtin_amdgcn_mfma_f32_16x16x32_bf16(kf, qf[0][kk], s[0][kg], 0, 0, 0);
                s[1][kg] = __builtin_amdgcn_mfma_f32_16x16x32_bf16(kf, qf[1][kk], s[1][kg], 0, 0, 0);
            }
        }

        short8 pf[2][2];
        #pragma unroll
        for (int qs = 0; qs < 2; ++qs) {
            int4 mv[4];
            #pragma unroll
            for (int kg = 0; kg < 4; ++kg)
                mv[kg] = *(const int4*)(mq + (size_t)qs*16*Sn + kt*KT + kg*16 + G*4);
            float ev[16];
            #pragma unroll
            for (int kg = 0; kg < 4; ++kg) {
                int ma[4] = {mv[kg].x, mv[kg].y, mv[kg].z, mv[kg].w};
                #pragma unroll
                for (int r = 0; r < 4; ++r) {
                    float tt = ma[r] ? 0.f : s[qs][kg][r];
                    ev[kg*4 + r] = fexp2(tt);
                }
            }
            lsum[qs] += (((ev[0]+ev[1])+(ev[2]+ev[3])) + ((ev[4]+ev[5])+(ev[6]+ev[7])))
                      + (((ev[8]+ev[9])+(ev[10]+ev[11])) + ((ev[12]+ev[13])+(ev[14]+ev[15])));
            #pragma unroll
            for (int hh = 0; hh < 2; ++hh) {
                union { unsigned u[4]; short8 v; } pu;
                pu.u[0] = pack_bf2(ev[hh*8+0], ev[hh*8+1]);
                pu.u[1] = pack_bf2(ev[hh*8+2], ev[hh*8+3]);
                pu.u[2] = pack_bf2(ev[hh*8+4], ev[hh*8+5]);
                pu.u[3] = pack_bf2(ev[hh*8+6], ev[hh*8+7]);
                pf[qs][hh] = pu.v;
            }
        }

        #pragma unroll
        for (int hh = 0; hh < 2; ++hh) {
            short8 vf[4];
            #pragma unroll
            for (int dg = 0; dg < 4; ++dg)
                vf[dg] = *(const short8*)&Vts[(dg*16 + li) * STR + hh*32 + G*8];
            #pragma unroll
            for (int qs = 0; qs < 2; ++qs)
                #pragma unroll
                for (int dg = 0; dg < 4; ++dg)
                    acc_o[qs][dg] = __builtin_amdgcn_mfma_f32_16x16x32_bf16(pf[qs][hh], vf[dg], acc_o[qs][dg], 0, 0, 0);
        }
    }

    #pragma unroll
    for (int qs = 0; qs < 2; ++qs) {
        float v = lsum[qs];
        v += __shfl_xor(v, 16, 64);
        v += __shfl_xor(v, 32, 64);
        lsum[qs] = v;
    }

    #pragma unroll
    for (int qs = 0; qs < 2; ++qs) {
        #pragma unroll
        for (int r = 0; r < 4; ++r) {
            float lv = __shfl(lsum[qs], (l & 48) | (G * 4 + r), 64);
            float inv = 1.f / lv;
            int qg = q0 + w*32 + qs*16 + G*4 + r;
            float* ob = out + ((size_t)b * Sn + qg) * Dn + h * DHn;
            #pragma unroll
            for (int dg = 0; dg < 4; ++dg)
                ob[dg*16 + li] = acc_o[qs][dg][r] * inv;
        }
    }
}

// residual + LayerNorm, in-place on d_out
__global__ __launch_bounds__(256)
void ln_kernel(const float* __restrict__ qin, const float* __restrict__ gamma,
               const float* __restrict__ beta, float* __restrict__ out)
{
    const int row = blockIdx.x;
    const int t   = threadIdx.x;
    const size_t base = (size_t)row * Dn + t * 4;

    float4 c = *(const float4*)(out + base);
    float4 r = *(const float4*)(qin + base);
    float4 v = make_float4(c.x + r.x, c.y + r.y, c.z + r.z, c.w + r.w);

    float sum = v.x + v.y + v.z + v.w;
    float sq  = v.x * v.x + v.y * v.y + v.z * v.z + v.w * v.w;
    #pragma unroll
    for (int off = 32; off >= 1; off >>= 1) {
        sum += __shfl_xor(sum, off, 64);
        sq  += __shfl_xor(sq,  off, 64);
    }
    __shared__ float as_[4], aq_[4];
    const int wid = t >> 6, ln = t & 63;
    if (ln == 0) { as_[wid] = sum; aq_[wid] = sq; }
    __syncthreads();
    sum = as_[0] + as_[1] + as_[2] + as_[3];
    sq  = aq_[0] + aq_[1] + aq_[2] + aq_[3];

    const float mean = sum * (1.f / Dn);
    const float var  = sq * (1.f / Dn) - mean * mean;
    const float rstd = rsqrtf(var + 1e-5f);

    float4 ga = *(const float4*)(gamma + t * 4);
    float4 be = *(const float4*)(beta + t * 4);
    float4 o;
    o.x = (v.x - mean) * rstd * ga.x + be.x;
    o.y = (v.y - mean) * rstd * ga.y + be.y;
    o.z = (v.z - mean) * rstd * ga.z + be.z;
    o.w = (v.w - mean) * rstd * ga.w + be.w;
    *(float4*)(out + base) = o;
}

extern "C" void kernel_launch(void* const* d_in, const int* in_sizes, int n_in,
                              void* d_out, int out_size, void* d_ws, size_t ws_size,
                              hipStream_t stream) {
    const float* q     = (const float*)d_in[0];
    // d_in[1] (k), d_in[2] (v) ignored: reference bug preserved
    const int*   masks = (const int*)d_in[3];
    const float* pQ    = (const float*)d_in[4];
    const float* pK    = (const float*)d_in[5];
    const float* pV    = (const float*)d_in[6];
    const float* gamma = (const float*)d_in[7];
    const float* beta  = (const float*)d_in[8];
    float* out = (float*)d_out;
    (void)in_sizes; (void)n_in; (void)out_size;

    const size_t elems = (size_t)Bn * Hn * Sn * DHn;            // 8,388,608
    const size_t kvbytes = elems * 2 * sizeof(ushort);          // 32 MiB
    const size_t need3 = kvbytes + (size_t)4 * Sn * 32 * 8;     // +2 MiB mask bits

    if (ws_size >= need3) {
        ushort* Kw = (ushort*)d_ws;
        ushort* Vw = Kw + elems;
        unsigned long long* mpack = (unsigned long long*)((char*)d_ws + kvbytes);
        prep_fused<<<6144, 256, 0, stream>>>(q, pK, pV, masks, Kw, Vw, mpack);
        attn_fast6<<<512, 256, 0, stream>>>(q, mpack, pQ, Kw, Vw, out);
    } else if (ws_size >= kvbytes) {
        ushort* Kbf = (ushort*)d_ws;
        ushort* Vtw = Kbf + elems;
        prep_kv<<<dim3(Sn / 64, Bn * Hn), 256, 0, stream>>>(q, pK, pV, Kbf, Vtw);
        attn_fast2<<<dim3(Sn / 128, Bn * Hn), 256, 0, stream>>>(q, masks, pQ, Kbf, Vtw, out);
    }
    ln_kernel<<<Bn * Sn, 256, 0, stream>>>(q, gamma, beta, out);
}